// Round 5
// baseline (1000.155 us; speedup 1.0000x reference)
//
#include <hip/hip_runtime.h>
#include <stdint.h>

// Problem constants (fixed by the reference)
constexpr int NN = 131072;          // coarse nodes
constexpr int EE = 1048576;         // edges
constexpr int NF = 4 * NN;          // fine nodes = 524288
constexpr int KK = 3 * NF;          // unpool entries = 1572864

constexpr int NBLK = 256;           // blocks per sort pass
constexpr int SH_E = 6;             // 64 nodes/bin  -> 2048 bins (E side)
constexpr int SH_K = 7;             // 128 nodes/bin -> 4096 bins (K side)
constexpr int NB_E = NN >> SH_E;    // 2048
constexpr int NB_K = NF >> SH_K;    // 4096
constexpr int EPT_E = EE / NBLK / 256;  // 16 edges/thread
constexpr int EPT_K = KK / NBLK / 256;  // 24 entries/thread

typedef __attribute__((ext_vector_type(8))) short bf16x8;
typedef __attribute__((ext_vector_type(4))) float f32x4;

__device__ inline uint32_t bf16rn(float f) {
    uint32_t u = __float_as_uint(f);
    return (u + 0x7FFFu + ((u >> 16) & 1u)) >> 16;
}
__device__ inline uint32_t pack2(float lo, float hi) {
    return bf16rn(lo) | (bf16rn(hi) << 16);
}
__device__ inline float bf_lo(uint32_t v) { return __uint_as_float(v << 16); }
__device__ inline float bf_hi(uint32_t v) { return __uint_as_float(v & 0xFFFF0000u); }

// ---------------------------------------------------------------------------
// 1) Transpose x = [a;b] (128 x N, f32) -> xTb (N x 128, bf16, node-major)
// ---------------------------------------------------------------------------
__global__ __launch_bounds__(256) void k_transpose(
    const float* __restrict__ a, const float* __restrict__ b,
    uint32_t* __restrict__ xTb)
{
    __shared__ float tile[128][33];
    int i0 = blockIdx.x * 32;
    for (int f = threadIdx.x; f < 128 * 32; f += 256) {
        int c = f >> 5, j = f & 31;
        const float* src = (c < 64) ? a : b;
        tile[c][j] = src[(size_t)(c & 63) * NN + i0 + j];
    }
    __syncthreads();
    for (int f = threadIdx.x; f < 64 * 32; f += 256) {
        int p = f & 63, j = f >> 6;
        xTb[(size_t)(i0 + j) * 64 + p] = pack2(tile[2 * p][j], tile[2 * p + 1][j]);
    }
}

// ---------------------------------------------------------------------------
// 2) Deterministic bin split (radix-style, ZERO global atomics)
//    pass1: per-block LDS histogram over bins -> histG[bin*NBLK + blk]
//    scan : exclusive scan of histG (in place)
//    pass2: LDS cursors from scanned histG; write packed pairs to exact slots
// ---------------------------------------------------------------------------
template<int NB, int EPT>
__global__ __launch_bounds__(256) void k_sortpass1(
    const int* __restrict__ idx, int shift, int* __restrict__ histG)
{
    __shared__ int hist[NB];
    for (int f = threadIdx.x; f < NB; f += 256) hist[f] = 0;
    __syncthreads();
    int base = blockIdx.x * (256 * EPT);
#pragma unroll
    for (int u = 0; u < EPT; ++u) {
        int b = idx[base + u * 256 + threadIdx.x] >> shift;
        atomicAdd(&hist[b], 1);
    }
    __syncthreads();
    for (int f = threadIdx.x; f < NB; f += 256)
        histG[f * NBLK + blockIdx.x] = hist[f];
}

// chunk = 2048 per block
__global__ __launch_bounds__(256) void k_scan_bsum(
    const int* __restrict__ cnt, int* __restrict__ bsum)
{
    __shared__ int s[256];
    int base = blockIdx.x * 2048;
    int sum = 0;
    for (int j = threadIdx.x; j < 2048; j += 256) sum += cnt[base + j];
    s[threadIdx.x] = sum;
    __syncthreads();
    for (int o = 128; o > 0; o >>= 1) {
        if (threadIdx.x < o) s[threadIdx.x] += s[threadIdx.x + o];
        __syncthreads();
    }
    if (threadIdx.x == 0) bsum[blockIdx.x] = s[0];
}

__global__ __launch_bounds__(512) void k_scan_exc(int* __restrict__ bsum, int nblk)
{
    __shared__ int s[512];
    int t = threadIdx.x;
    s[t] = (t < nblk) ? bsum[t] : 0;
    __syncthreads();
    for (int o = 1; o < 512; o <<= 1) {
        int v = (t >= o) ? s[t - o] : 0;
        __syncthreads();
        s[t] += v;
        __syncthreads();
    }
    if (t < nblk) bsum[t] = (t == 0) ? 0 : s[t - 1];
}

// in-place exclusive scan finalize; writes offs[nb] = total
__global__ __launch_bounds__(256) void k_scan_final(
    int* __restrict__ offs, int nb, const int* __restrict__ bsum)
{
    __shared__ int ts[256];
    int base = blockIdx.x * 2048 + threadIdx.x * 8;
    int loc[8];
    int sum = 0;
#pragma unroll
    for (int u = 0; u < 8; ++u) {
        int v = offs[base + u];
        loc[u] = sum;
        sum += v;
    }
    ts[threadIdx.x] = sum;
    __syncthreads();
    for (int o = 1; o < 256; o <<= 1) {
        int v = (threadIdx.x >= o) ? ts[threadIdx.x - o] : 0;
        __syncthreads();
        ts[threadIdx.x] += v;
        __syncthreads();
    }
    int texc = (threadIdx.x == 0) ? 0 : ts[threadIdx.x - 1];
    int bb = bsum[blockIdx.x];
#pragma unroll
    for (int u = 0; u < 8; ++u) offs[base + u] = bb + texc + loc[u];
    if (blockIdx.x == gridDim.x - 1 && threadIdx.x == 255) offs[nb] = bb + ts[255];
}

// pack: payload (17 bits) | bucket-local (<<17)
template<int NB, int EPT>
__global__ __launch_bounds__(256) void k_sortpass2(
    const int* __restrict__ idx, const int* __restrict__ payload, int shift,
    const int* __restrict__ offsG, uint32_t* __restrict__ pairs)
{
    __shared__ int curs[NB];
    for (int f = threadIdx.x; f < NB; f += 256)
        curs[f] = offsG[f * NBLK + blockIdx.x];
    __syncthreads();
    int lmask = (1 << shift) - 1;
    int base = blockIdx.x * (256 * EPT);
#pragma unroll
    for (int u = 0; u < EPT; ++u) {
        int e = base + u * 256 + threadIdx.x;
        int bk = idx[e];
        int pos = atomicAdd(&curs[bk >> shift], 1);
        pairs[pos] = (uint32_t)payload[e] | ((uint32_t)(bk & lmask) << 17);
    }
}

// ---------------------------------------------------------------------------
// 3) Bin-wise pull aggregation: block owns 64 coarse nodes; LDS f32 ds_add
//    accumulators; aggB written once, coalesced. Wave handles 1 pair with 64
//    lanes (lane = feature pair); 4 pairs in flight for latency hiding.
// ---------------------------------------------------------------------------
__global__ __launch_bounds__(256) void k_aggbin(
    const uint32_t* __restrict__ xTb, const int* __restrict__ offsE,
    const uint32_t* __restrict__ pairsE, uint32_t* __restrict__ aggB)
{
    __shared__ float acc[64 * 128];
    for (int f = threadIdx.x; f < 64 * 128; f += 256) acc[f] = 0.f;
    __syncthreads();
    int bin = blockIdx.x;
    int beg = offsE[bin * NBLK], end = offsE[(bin + 1) * NBLK];
    int cnt = end - beg;
    int w = threadIdx.x >> 6, lane = threadIdx.x & 63;
    for (int i0 = 4 * w; i0 < cnt; i0 += 16) {
        int m = min(4, cnt - i0);
        uint32_t pr[4], v[4];
#pragma unroll
        for (int j = 0; j < 4; ++j)
            pr[j] = pairsE[beg + i0 + min(j, m - 1)];
#pragma unroll
        for (int j = 0; j < 4; ++j)
            v[j] = xTb[(size_t)(pr[j] & 0x1FFFF) * 64 + lane];
#pragma unroll
        for (int j = 0; j < 4; ++j) {
            if (j < m) {
                int l = pr[j] >> 17;
                atomicAdd(&acc[l * 128 + 2 * lane], bf_lo(v[j]));
                atomicAdd(&acc[l * 128 + 2 * lane + 1], bf_hi(v[j]));
            }
        }
    }
    __syncthreads();
    for (int nl = w; nl < 64; nl += 4) {
        int node = bin * 64 + nl;
        aggB[(size_t)node * 64 + lane] =
            pack2(acc[nl * 128 + 2 * lane], acc[nl * 128 + 2 * lane + 1]);
    }
}

// ---------------------------------------------------------------------------
// 4) MFMA GEMM: h = relu([Wself|Wneigh] @ [x;agg] + bias), bf16 in/out.
//    C/D: col(node)=l&15, row(c)=(l>>4)*4+r  [m89-verified layout]
// ---------------------------------------------------------------------------
__global__ __launch_bounds__(256) void k_gemm(
    const uint32_t* __restrict__ xTb, const uint32_t* __restrict__ aggB,
    const float* __restrict__ Wself, const float* __restrict__ Wneigh,
    const float* __restrict__ bias, uint32_t* __restrict__ hT)
{
    int lane = threadIdx.x & 63;
    int wid = blockIdx.x * 4 + (threadIdx.x >> 6);
    int lr = lane & 15, lq = lane >> 4;

    bf16x8 wf[4][8];
#pragma unroll
    for (int mt = 0; mt < 4; ++mt) {
#pragma unroll
        for (int kt = 0; kt < 8; ++kt) {
            const float* W = (kt < 4) ? Wself : Wneigh;
            const float* p = W + (size_t)(mt * 16 + lr) * 128 + (kt & 3) * 32 + lq * 8;
            bf16x8 v;
#pragma unroll
            for (int j = 0; j < 8; ++j) v[j] = (short)bf16rn(p[j]);
            wf[mt][kt] = v;
        }
    }
    float bv[4][4];
#pragma unroll
    for (int mt = 0; mt < 4; ++mt)
#pragma unroll
        for (int r = 0; r < 4; ++r)
            bv[mt][r] = bias[mt * 16 + lq * 4 + r];

    const int NG = NN / 16;
    int stride = gridDim.x * 4;
    for (int g = wid; g < NG; g += stride) {
        int n = g * 16 + lr;
        const uint32_t* xr = xTb + (size_t)n * 64 + lq * 4;
        const uint32_t* ar = aggB + (size_t)n * 64 + lq * 4;
        bf16x8 bq[8];
#pragma unroll
        for (int kt = 0; kt < 4; ++kt)
            bq[kt] = *reinterpret_cast<const bf16x8*>(xr + kt * 16);
#pragma unroll
        for (int kt = 0; kt < 4; ++kt)
            bq[4 + kt] = *reinterpret_cast<const bf16x8*>(ar + kt * 16);
#pragma unroll
        for (int mt = 0; mt < 4; ++mt) {
            f32x4 acc = {0.f, 0.f, 0.f, 0.f};
#pragma unroll
            for (int kt = 0; kt < 8; ++kt)
                acc = __builtin_amdgcn_mfma_f32_16x16x32_bf16(wf[mt][kt], bq[kt], acc, 0, 0, 0);
            uint32_t u0 = pack2(fmaxf(acc[0] + bv[mt][0], 0.f), fmaxf(acc[1] + bv[mt][1], 0.f));
            uint32_t u1 = pack2(fmaxf(acc[2] + bv[mt][2], 0.f), fmaxf(acc[3] + bv[mt][3], 0.f));
            *reinterpret_cast<uint2*>(hT + (size_t)n * 32 + mt * 8 + lq * 2) = make_uint2(u0, u1);
        }
    }
}

// ---------------------------------------------------------------------------
// 5) Bin-wise unpool scatter-max: block owns 128 fine nodes; LDS u32 max
//    (bf16 >= 0 so bit max == numeric max); out written once, coalesced.
// ---------------------------------------------------------------------------
__global__ __launch_bounds__(256) void k_unpoolbin(
    const uint16_t* __restrict__ hT16, const int* __restrict__ offsK,
    const uint32_t* __restrict__ pairsK, float* __restrict__ out)
{
    __shared__ uint32_t acc[128 * 65];   // +pad for conflict-free epilogue read
    for (int f = threadIdx.x; f < 128 * 65; f += 256) acc[f] = 0u;
    __syncthreads();
    int bin = blockIdx.x;
    int beg = offsK[bin * NBLK], end = offsK[(bin + 1) * NBLK];
    int cnt = end - beg;
    int w = threadIdx.x >> 6, lane = threadIdx.x & 63;
    for (int i0 = 4 * w; i0 < cnt; i0 += 16) {
        int m = min(4, cnt - i0);
        uint32_t pr[4], v[4];
#pragma unroll
        for (int j = 0; j < 4; ++j)
            pr[j] = pairsK[beg + i0 + min(j, m - 1)];
#pragma unroll
        for (int j = 0; j < 4; ++j)
            v[j] = hT16[(size_t)(pr[j] & 0x1FFFF) * 64 + lane];
#pragma unroll
        for (int j = 0; j < 4; ++j) {
            if (j < m) {
                int l = pr[j] >> 17;
                atomicMax(&acc[l * 65 + lane], v[j]);
            }
        }
    }
    __syncthreads();
    int j0 = bin << 7;
    for (int f = threadIdx.x; f < 64 * 128; f += 256) {
        int c = f >> 7, j = f & 127;
        out[(size_t)c * NF + j0 + j] = __uint_as_float(acc[j * 65 + c] << 16);
    }
}

// ---------------------------------------------------------------------------
extern "C" void kernel_launch(void* const* d_in, const int* in_sizes, int n_in,
                              void* d_out, int out_size, void* d_ws, size_t ws_size,
                              hipStream_t stream)
{
    const float* a      = (const float*)d_in[0];
    const float* b      = (const float*)d_in[1];
    const float* Wself  = (const float*)d_in[2];
    const float* Wneigh = (const float*)d_in[3];
    const float* bias   = (const float*)d_in[4];
    const int* gather_i = (const int*)d_in[5];
    const int* reduce_i = (const int*)d_in[6];
    const int* up_src   = (const int*)d_in[7];
    const int* up_dst   = (const int*)d_in[8];
    float* out = (float*)d_out;

    // workspace layout (u32 elems); pairsE overlays hT (dead before gemm)
    uint32_t* xTb   = (uint32_t*)d_ws;                   // NN*64  = 8,388,608
    uint32_t* aggB  = xTb + (size_t)NN * 64;             // NN*64
    uint32_t* hT    = aggB + (size_t)NN * 64;            // NN*32  = 4,194,304
    uint32_t* pairsK= hT + (size_t)NN * 32;              // KK     = 1,572,864
    int* offsE      = (int*)(pairsK + KK);               // NB_E*NBLK+1 = 524,289
    int* offsK      = offsE + (size_t)NB_E * NBLK + 1;   // NB_K*NBLK+1 = 1,048,577
    int* bsum       = offsK + (size_t)NB_K * NBLK + 1;   // 1024
    uint32_t* pairsE= hT;                                // EE (overlay)

    size_t need = ((size_t)NN * 160 + KK +
                   (size_t)NB_E * NBLK + 1 + (size_t)NB_K * NBLK + 1 + 1024) * 4;
    if (ws_size < need) return;  // fail visibly (output stays poisoned)

    // 1) transpose + bf16 pack
    k_transpose<<<NN / 32, 256, 0, stream>>>(a, b, xTb);

    // 2) E-side deterministic bin split (bin = node>>6)
    k_sortpass1<NB_E, EPT_E><<<NBLK, 256, 0, stream>>>(reduce_i, SH_E, offsE);
    k_scan_bsum<<<NB_E * NBLK / 2048, 256, 0, stream>>>(offsE, bsum);
    k_scan_exc<<<1, 512, 0, stream>>>(bsum, NB_E * NBLK / 2048);
    k_scan_final<<<NB_E * NBLK / 2048, 256, 0, stream>>>(offsE, NB_E * NBLK, bsum);
    k_sortpass2<NB_E, EPT_E><<<NBLK, 256, 0, stream>>>(reduce_i, gather_i, SH_E, offsE, pairsE);

    // 3) K-side deterministic bin split (bin = fine>>7)
    k_sortpass1<NB_K, EPT_K><<<NBLK, 256, 0, stream>>>(up_dst, SH_K, offsK);
    k_scan_bsum<<<NB_K * NBLK / 2048, 256, 0, stream>>>(offsK, bsum);
    k_scan_exc<<<1, 512, 0, stream>>>(bsum, NB_K * NBLK / 2048);
    k_scan_final<<<NB_K * NBLK / 2048, 256, 0, stream>>>(offsK, NB_K * NBLK, bsum);
    k_sortpass2<NB_K, EPT_K><<<NBLK, 256, 0, stream>>>(up_dst, up_src, SH_K, offsK, pairsK);

    // 4) bin-wise aggregation (LDS f32 accumulate, coalesced write-once)
    k_aggbin<<<NB_E, 256, 0, stream>>>(xTb, offsE, pairsE, aggB);

    // 5) MFMA GEMM + bias + relu -> hT (bf16)
    k_gemm<<<512, 256, 0, stream>>>(xTb, aggB, Wself, Wneigh, bias, hT);

    // 6) bin-wise unpool max (LDS u32 max, coalesced write-once)
    k_unpoolbin<<<NB_K, 256, 0, stream>>>((const uint16_t*)hT, offsK, pairsK, out);
}

// Round 6
// 323.405 us; speedup vs baseline: 3.0926x; 3.0926x over previous
//
#include <hip/hip_runtime.h>
#include <stdint.h>

// Problem constants (fixed by the reference)
constexpr int NN = 131072;          // coarse nodes
constexpr int EE = 1048576;         // edges
constexpr int NF = 4 * NN;          // fine nodes = 524288
constexpr int KK = 3 * NF;          // unpool entries = 1572864

constexpr int NBLK = 256;           // blocks per sort pass
constexpr int SH_E = 6;             // 64 nodes/bin  -> 2048 bins (E side)
constexpr int SH_K = 7;             // 128 nodes/bin -> 4096 bins (K side)
constexpr int NB_E = NN >> SH_E;    // 2048
constexpr int NB_K = NF >> SH_K;    // 4096
constexpr int EPT_E = EE / NBLK / 256;  // 16 edges/thread
constexpr int EPT_K = KK / NBLK / 256;  // 24 entries/thread
constexpr int CAP_E = 2048;         // >> mean 512 + 10 sigma (binomial sd ~23)
constexpr int CAP_K = 1024;         // >> mean 384 + 10 sigma (sd ~20)

typedef __attribute__((ext_vector_type(8))) short bf16x8;
typedef __attribute__((ext_vector_type(4))) float f32x4;

__device__ inline uint32_t bf16rn(float f) {
    uint32_t u = __float_as_uint(f);
    return (u + 0x7FFFu + ((u >> 16) & 1u)) >> 16;
}
__device__ inline uint32_t pack2(float lo, float hi) {
    return bf16rn(lo) | (bf16rn(hi) << 16);
}
__device__ inline float bf_lo(uint32_t v) { return __uint_as_float(v << 16); }
__device__ inline float bf_hi(uint32_t v) { return __uint_as_float(v & 0xFFFF0000u); }

// ---------------------------------------------------------------------------
// 1) Transpose x = [a;b] (128 x N, f32) -> xTb (N x 128, bf16, node-major)
// ---------------------------------------------------------------------------
__global__ __launch_bounds__(256) void k_transpose(
    const float* __restrict__ a, const float* __restrict__ b,
    uint32_t* __restrict__ xTb)
{
    __shared__ float tile[128][33];
    int i0 = blockIdx.x * 32;
    for (int f = threadIdx.x; f < 128 * 32; f += 256) {
        int c = f >> 5, j = f & 31;
        const float* src = (c < 64) ? a : b;
        tile[c][j] = src[(size_t)(c & 63) * NN + i0 + j];
    }
    __syncthreads();
    for (int f = threadIdx.x; f < 64 * 32; f += 256) {
        int p = f & 63, j = f >> 6;
        xTb[(size_t)(i0 + j) * 64 + p] = pack2(tile[2 * p][j], tile[2 * p + 1][j]);
    }
}

// ---------------------------------------------------------------------------
// 2) Deterministic bin split (radix-style, ZERO global atomics)
// ---------------------------------------------------------------------------
template<int NB, int EPT>
__global__ __launch_bounds__(256) void k_sortpass1(
    const int* __restrict__ idx, int shift, int* __restrict__ histG)
{
    __shared__ int hist[NB];
    for (int f = threadIdx.x; f < NB; f += 256) hist[f] = 0;
    __syncthreads();
    int base = blockIdx.x * (256 * EPT);
#pragma unroll
    for (int u = 0; u < EPT; ++u) {
        int b = idx[base + u * 256 + threadIdx.x] >> shift;
        atomicAdd(&hist[b], 1);
    }
    __syncthreads();
    for (int f = threadIdx.x; f < NB; f += 256)
        histG[f * NBLK + blockIdx.x] = hist[f];
}

// chunk = 2048 per block
__global__ __launch_bounds__(256) void k_scan_bsum(
    const int* __restrict__ cnt, int* __restrict__ bsum)
{
    __shared__ int s[256];
    int base = blockIdx.x * 2048;
    int sum = 0;
    for (int j = threadIdx.x; j < 2048; j += 256) sum += cnt[base + j];
    s[threadIdx.x] = sum;
    __syncthreads();
    for (int o = 128; o > 0; o >>= 1) {
        if (threadIdx.x < o) s[threadIdx.x] += s[threadIdx.x + o];
        __syncthreads();
    }
    if (threadIdx.x == 0) bsum[blockIdx.x] = s[0];
}

__global__ __launch_bounds__(512) void k_scan_exc(int* __restrict__ bsum, int nblk)
{
    __shared__ int s[512];
    int t = threadIdx.x;
    s[t] = (t < nblk) ? bsum[t] : 0;
    __syncthreads();
    for (int o = 1; o < 512; o <<= 1) {
        int v = (t >= o) ? s[t - o] : 0;
        __syncthreads();
        s[t] += v;
        __syncthreads();
    }
    if (t < nblk) bsum[t] = (t == 0) ? 0 : s[t - 1];
}

// in-place exclusive scan finalize; writes offs[nb] = total
__global__ __launch_bounds__(256) void k_scan_final(
    int* __restrict__ offs, int nb, const int* __restrict__ bsum)
{
    __shared__ int ts[256];
    int base = blockIdx.x * 2048 + threadIdx.x * 8;
    int loc[8];
    int sum = 0;
#pragma unroll
    for (int u = 0; u < 8; ++u) {
        int v = offs[base + u];
        loc[u] = sum;
        sum += v;
    }
    ts[threadIdx.x] = sum;
    __syncthreads();
    for (int o = 1; o < 256; o <<= 1) {
        int v = (threadIdx.x >= o) ? ts[threadIdx.x - o] : 0;
        __syncthreads();
        ts[threadIdx.x] += v;
        __syncthreads();
    }
    int texc = (threadIdx.x == 0) ? 0 : ts[threadIdx.x - 1];
    int bb = bsum[blockIdx.x];
#pragma unroll
    for (int u = 0; u < 8; ++u) offs[base + u] = bb + texc + loc[u];
    if (blockIdx.x == gridDim.x - 1 && threadIdx.x == 255) offs[nb] = bb + ts[255];
}

// pack: payload (17 bits) | bucket-local (<<17)
template<int NB, int EPT>
__global__ __launch_bounds__(256) void k_sortpass2(
    const int* __restrict__ idx, const int* __restrict__ payload, int shift,
    const int* __restrict__ offsG, uint32_t* __restrict__ pairs)
{
    __shared__ int curs[NB];
    for (int f = threadIdx.x; f < NB; f += 256)
        curs[f] = offsG[f * NBLK + blockIdx.x];
    __syncthreads();
    int lmask = (1 << shift) - 1;
    int base = blockIdx.x * (256 * EPT);
#pragma unroll
    for (int u = 0; u < EPT; ++u) {
        int e = base + u * 256 + threadIdx.x;
        int bk = idx[e];
        int pos = atomicAdd(&curs[bk >> shift], 1);
        pairs[pos] = (uint32_t)payload[e] | ((uint32_t)(bk & lmask) << 17);
    }
}

// ---------------------------------------------------------------------------
// 3) Bin-wise aggregation via in-LDS counting sort + register accumulation.
//    Block owns 64 coarse nodes. LDS: sorted source list (CSR). Each wave
//    owns nodes round-robin; lane = feature pair; acc in REGISTERS; aggB
//    written once, coalesced. No global atomics, no LDS accumulate.
// ---------------------------------------------------------------------------
__global__ __launch_bounds__(256) void k_aggcsr(
    const uint32_t* __restrict__ xTb, const int* __restrict__ offsE,
    const uint32_t* __restrict__ pairsE, uint32_t* __restrict__ aggB)
{
    __shared__ int list[CAP_E];
    __shared__ int offs[65];
    __shared__ int curs[64];
    __shared__ int cnt_s;
    int bin = blockIdx.x;
    if (threadIdx.x == 0) {
        int beg = offsE[bin * NBLK];
        cnt_s = min(offsE[(bin + 1) * NBLK] - beg, CAP_E);
    }
    if (threadIdx.x < 64) curs[threadIdx.x] = 0;
    __syncthreads();
    int beg = offsE[bin * NBLK];
    int cnt = cnt_s;
    // histogram by local node
    for (int i = threadIdx.x; i < cnt; i += 256)
        atomicAdd(&curs[(pairsE[beg + i] >> 17) & 63], 1);
    __syncthreads();
    if (threadIdx.x == 0) {
        int run = 0;
        for (int j = 0; j < 64; ++j) {
            offs[j] = run;
            run += curs[j];
            curs[j] = offs[j];
        }
        offs[64] = run;
    }
    __syncthreads();
    // scatter into sorted list (src only)
    for (int i = threadIdx.x; i < cnt; i += 256) {
        uint32_t u = pairsE[beg + i];
        int p = atomicAdd(&curs[(u >> 17) & 63], 1);
        list[p] = (int)(u & 0x1FFFF);
    }
    __syncthreads();
    // consume: register accumulate per node
    int w = threadIdx.x >> 6, lane = threadIdx.x & 63;
    for (int nl = w; nl < 64; nl += 4) {
        int s = offs[nl], e2 = offs[nl + 1];
        float sx = 0.f, sy = 0.f;
        int q = s;
        for (; q + 3 < e2; q += 4) {
            int s0 = list[q], s1 = list[q + 1], s2 = list[q + 2], s3 = list[q + 3];
            uint32_t v0 = xTb[(size_t)s0 * 64 + lane];
            uint32_t v1 = xTb[(size_t)s1 * 64 + lane];
            uint32_t v2 = xTb[(size_t)s2 * 64 + lane];
            uint32_t v3 = xTb[(size_t)s3 * 64 + lane];
            sx += bf_lo(v0) + bf_lo(v1) + bf_lo(v2) + bf_lo(v3);
            sy += bf_hi(v0) + bf_hi(v1) + bf_hi(v2) + bf_hi(v3);
        }
        for (; q < e2; ++q) {
            uint32_t v = xTb[(size_t)list[q] * 64 + lane];
            sx += bf_lo(v);
            sy += bf_hi(v);
        }
        aggB[(size_t)(bin * 64 + nl) * 64 + lane] = pack2(sx, sy);
    }
}

// ---------------------------------------------------------------------------
// 4) MFMA GEMM: h = relu([Wself|Wneigh] @ [x;agg] + bias), bf16 in/out.
//    C/D: col(node)=l&15, row(c)=(l>>4)*4+r  [m89-verified layout]
// ---------------------------------------------------------------------------
__global__ __launch_bounds__(256) void k_gemm(
    const uint32_t* __restrict__ xTb, const uint32_t* __restrict__ aggB,
    const float* __restrict__ Wself, const float* __restrict__ Wneigh,
    const float* __restrict__ bias, uint32_t* __restrict__ hT)
{
    int lane = threadIdx.x & 63;
    int wid = blockIdx.x * 4 + (threadIdx.x >> 6);
    int lr = lane & 15, lq = lane >> 4;

    bf16x8 wf[4][8];
#pragma unroll
    for (int mt = 0; mt < 4; ++mt) {
#pragma unroll
        for (int kt = 0; kt < 8; ++kt) {
            const float* W = (kt < 4) ? Wself : Wneigh;
            const float* p = W + (size_t)(mt * 16 + lr) * 128 + (kt & 3) * 32 + lq * 8;
            bf16x8 v;
#pragma unroll
            for (int j = 0; j < 8; ++j) v[j] = (short)bf16rn(p[j]);
            wf[mt][kt] = v;
        }
    }
    float bv[4][4];
#pragma unroll
    for (int mt = 0; mt < 4; ++mt)
#pragma unroll
        for (int r = 0; r < 4; ++r)
            bv[mt][r] = bias[mt * 16 + lq * 4 + r];

    const int NG = NN / 16;
    int stride = gridDim.x * 4;
    for (int g = wid; g < NG; g += stride) {
        int n = g * 16 + lr;
        const uint32_t* xr = xTb + (size_t)n * 64 + lq * 4;
        const uint32_t* ar = aggB + (size_t)n * 64 + lq * 4;
        bf16x8 bq[8];
#pragma unroll
        for (int kt = 0; kt < 4; ++kt)
            bq[kt] = *reinterpret_cast<const bf16x8*>(xr + kt * 16);
#pragma unroll
        for (int kt = 0; kt < 4; ++kt)
            bq[4 + kt] = *reinterpret_cast<const bf16x8*>(ar + kt * 16);
#pragma unroll
        for (int mt = 0; mt < 4; ++mt) {
            f32x4 acc = {0.f, 0.f, 0.f, 0.f};
#pragma unroll
            for (int kt = 0; kt < 8; ++kt)
                acc = __builtin_amdgcn_mfma_f32_16x16x32_bf16(wf[mt][kt], bq[kt], acc, 0, 0, 0);
            uint32_t u0 = pack2(fmaxf(acc[0] + bv[mt][0], 0.f), fmaxf(acc[1] + bv[mt][1], 0.f));
            uint32_t u1 = pack2(fmaxf(acc[2] + bv[mt][2], 0.f), fmaxf(acc[3] + bv[mt][3], 0.f));
            *reinterpret_cast<uint2*>(hT + (size_t)n * 32 + mt * 8 + lq * 2) = make_uint2(u0, u1);
        }
    }
}

// ---------------------------------------------------------------------------
// 5) Bin-wise unpool via in-LDS counting sort + register max.
//    Block owns 128 fine nodes; bf16 >= 0 so bit-max == numeric max.
// ---------------------------------------------------------------------------
__global__ __launch_bounds__(256) void k_unpoolcsr(
    const uint16_t* __restrict__ hT16, const int* __restrict__ offsK,
    const uint32_t* __restrict__ pairsK, float* __restrict__ out)
{
    __shared__ int list[CAP_K];
    __shared__ int offs[129];
    __shared__ int curs[128];
    __shared__ uint16_t buf[128][65];
    __shared__ int cnt_s;
    int bin = blockIdx.x;
    if (threadIdx.x == 0) {
        int beg = offsK[bin * NBLK];
        cnt_s = min(offsK[(bin + 1) * NBLK] - beg, CAP_K);
    }
    if (threadIdx.x < 128) curs[threadIdx.x] = 0;
    __syncthreads();
    int beg = offsK[bin * NBLK];
    int cnt = cnt_s;
    for (int i = threadIdx.x; i < cnt; i += 256)
        atomicAdd(&curs[(pairsK[beg + i] >> 17) & 127], 1);
    __syncthreads();
    if (threadIdx.x == 0) {
        int run = 0;
        for (int j = 0; j < 128; ++j) {
            offs[j] = run;
            run += curs[j];
            curs[j] = offs[j];
        }
        offs[128] = run;
    }
    __syncthreads();
    for (int i = threadIdx.x; i < cnt; i += 256) {
        uint32_t u = pairsK[beg + i];
        int p = atomicAdd(&curs[(u >> 17) & 127], 1);
        list[p] = (int)(u & 0x1FFFF);
    }
    __syncthreads();
    int w = threadIdx.x >> 6, lane = threadIdx.x & 63;
    for (int nl = w; nl < 128; nl += 4) {
        int s = offs[nl], e2 = offs[nl + 1];
        uint32_t m = 0;
        int q = s;
        for (; q + 1 < e2; q += 2) {
            uint32_t v0 = hT16[(size_t)list[q] * 64 + lane];
            uint32_t v1 = hT16[(size_t)list[q + 1] * 64 + lane];
            m = max(m, max(v0, v1));
        }
        for (; q < e2; ++q)
            m = max(m, (uint32_t)hT16[(size_t)list[q] * 64 + lane]);
        buf[nl][lane] = (uint16_t)m;
    }
    __syncthreads();
    int j0 = bin << 7;
    for (int f = threadIdx.x; f < 64 * 128; f += 256) {
        int c = f >> 7, j = f & 127;
        out[(size_t)c * NF + j0 + j] = __uint_as_float(((uint32_t)buf[j][c]) << 16);
    }
}

// ---------------------------------------------------------------------------
extern "C" void kernel_launch(void* const* d_in, const int* in_sizes, int n_in,
                              void* d_out, int out_size, void* d_ws, size_t ws_size,
                              hipStream_t stream)
{
    const float* a      = (const float*)d_in[0];
    const float* b      = (const float*)d_in[1];
    const float* Wself  = (const float*)d_in[2];
    const float* Wneigh = (const float*)d_in[3];
    const float* bias   = (const float*)d_in[4];
    const int* gather_i = (const int*)d_in[5];
    const int* reduce_i = (const int*)d_in[6];
    const int* up_src   = (const int*)d_in[7];
    const int* up_dst   = (const int*)d_in[8];
    float* out = (float*)d_out;

    // workspace layout (u32 elems); pairsE overlays hT (dead before gemm)
    uint32_t* xTb   = (uint32_t*)d_ws;                   // NN*64
    uint32_t* aggB  = xTb + (size_t)NN * 64;             // NN*64
    uint32_t* hT    = aggB + (size_t)NN * 64;            // NN*32
    uint32_t* pairsK= hT + (size_t)NN * 32;              // KK
    int* offsE      = (int*)(pairsK + KK);               // NB_E*NBLK+1
    int* offsK      = offsE + (size_t)NB_E * NBLK + 1;   // NB_K*NBLK+1
    int* bsum       = offsK + (size_t)NB_K * NBLK + 1;   // 1024
    uint32_t* pairsE= hT;                                // EE (overlay)

    size_t need = ((size_t)NN * 160 + KK +
                   (size_t)NB_E * NBLK + 1 + (size_t)NB_K * NBLK + 1 + 1024) * 4;
    if (ws_size < need) return;  // fail visibly (output stays poisoned)

    // 1) transpose + bf16 pack
    k_transpose<<<NN / 32, 256, 0, stream>>>(a, b, xTb);

    // 2) E-side deterministic bin split (bin = node>>6)
    k_sortpass1<NB_E, EPT_E><<<NBLK, 256, 0, stream>>>(reduce_i, SH_E, offsE);
    k_scan_bsum<<<NB_E * NBLK / 2048, 256, 0, stream>>>(offsE, bsum);
    k_scan_exc<<<1, 512, 0, stream>>>(bsum, NB_E * NBLK / 2048);
    k_scan_final<<<NB_E * NBLK / 2048, 256, 0, stream>>>(offsE, NB_E * NBLK, bsum);
    k_sortpass2<NB_E, EPT_E><<<NBLK, 256, 0, stream>>>(reduce_i, gather_i, SH_E, offsE, pairsE);

    // 3) K-side deterministic bin split (bin = fine>>7)
    k_sortpass1<NB_K, EPT_K><<<NBLK, 256, 0, stream>>>(up_dst, SH_K, offsK);
    k_scan_bsum<<<NB_K * NBLK / 2048, 256, 0, stream>>>(offsK, bsum);
    k_scan_exc<<<1, 512, 0, stream>>>(bsum, NB_K * NBLK / 2048);
    k_scan_final<<<NB_K * NBLK / 2048, 256, 0, stream>>>(offsK, NB_K * NBLK, bsum);
    k_sortpass2<NB_K, EPT_K><<<NBLK, 256, 0, stream>>>(up_dst, up_src, SH_K, offsK, pairsK);

    // 4) bin-wise aggregation (in-LDS CSR, register accumulate)
    k_aggcsr<<<NB_E, 256, 0, stream>>>(xTb, offsE, pairsE, aggB);

    // 5) MFMA GEMM + bias + relu -> hT (bf16)
    k_gemm<<<512, 256, 0, stream>>>(xTb, aggB, Wself, Wneigh, bias, hT);

    // 6) bin-wise unpool max (in-LDS CSR, register max)
    k_unpoolcsr<<<NB_K, 256, 0, stream>>>((const uint16_t*)hT, offsK, pairsK, out);
}

// Round 7
// 295.451 us; speedup vs baseline: 3.3852x; 1.0946x over previous
//
#include <hip/hip_runtime.h>
#include <stdint.h>

// Problem constants (fixed by the reference)
constexpr int NN = 131072;          // coarse nodes
constexpr int EE = 1048576;         // edges
constexpr int NF = 4 * NN;          // fine nodes = 524288
constexpr int KK = 3 * NF;          // unpool entries = 1572864

constexpr int NBLK = 256;           // blocks per sort pass
constexpr int SH_E = 6;             // 64 nodes/bin  -> 2048 bins (E side)
constexpr int SH_K = 7;             // 128 nodes/bin -> 4096 bins (K side)
constexpr int NB_E = NN >> SH_E;    // 2048
constexpr int NB_K = NF >> SH_K;    // 4096
constexpr int EPT_E = EE / NBLK / 256;  // 16 edges/thread
constexpr int EPT_K = KK / NBLK / 256;  // 24 entries/thread
constexpr int CAP_E = 2048;         // >> mean 512 + 10 sigma
constexpr int CAP_K = 1024;         // >> mean 384 + 10 sigma

typedef __attribute__((ext_vector_type(8))) short bf16x8;
typedef __attribute__((ext_vector_type(4))) float f32x4;

__device__ inline uint32_t bf16rn(float f) {
    uint32_t u = __float_as_uint(f);
    return (u + 0x7FFFu + ((u >> 16) & 1u)) >> 16;
}
__device__ inline uint32_t pack2(float lo, float hi) {
    return bf16rn(lo) | (bf16rn(hi) << 16);
}
__device__ inline float bf_lo(uint32_t v) { return __uint_as_float(v << 16); }
__device__ inline float bf_hi(uint32_t v) { return __uint_as_float(v & 0xFFFF0000u); }

// ---------------------------------------------------------------------------
// 1) Transpose x = [a;b] (128 x N, f32) -> xTb (N x 128, bf16, node-major)
// ---------------------------------------------------------------------------
__global__ __launch_bounds__(256) void k_transpose(
    const float* __restrict__ a, const float* __restrict__ b,
    uint32_t* __restrict__ xTb)
{
    __shared__ float tile[128][33];
    int i0 = blockIdx.x * 32;
    for (int f = threadIdx.x; f < 128 * 32; f += 256) {
        int c = f >> 5, j = f & 31;
        const float* src = (c < 64) ? a : b;
        tile[c][j] = src[(size_t)(c & 63) * NN + i0 + j];
    }
    __syncthreads();
    for (int f = threadIdx.x; f < 64 * 32; f += 256) {
        int p = f & 63, j = f >> 6;
        xTb[(size_t)(i0 + j) * 64 + p] = pack2(tile[2 * p][j], tile[2 * p + 1][j]);
    }
}

// ---------------------------------------------------------------------------
// 2) Deterministic bin split (radix-style, ZERO global atomics)
// ---------------------------------------------------------------------------
template<int NB, int EPT>
__global__ __launch_bounds__(256) void k_sortpass1(
    const int* __restrict__ idx, int shift, int* __restrict__ histG)
{
    __shared__ int hist[NB];
    for (int f = threadIdx.x; f < NB; f += 256) hist[f] = 0;
    __syncthreads();
    int base = blockIdx.x * (256 * EPT);
#pragma unroll
    for (int u = 0; u < EPT; ++u) {
        int b = idx[base + u * 256 + threadIdx.x] >> shift;
        atomicAdd(&hist[b], 1);
    }
    __syncthreads();
    for (int f = threadIdx.x; f < NB; f += 256)
        histG[f * NBLK + blockIdx.x] = hist[f];
}

// chunk = 2048 per block
__global__ __launch_bounds__(256) void k_scan_bsum(
    const int* __restrict__ cnt, int* __restrict__ bsum)
{
    __shared__ int s[256];
    int base = blockIdx.x * 2048;
    int sum = 0;
    for (int j = threadIdx.x; j < 2048; j += 256) sum += cnt[base + j];
    s[threadIdx.x] = sum;
    __syncthreads();
    for (int o = 128; o > 0; o >>= 1) {
        if (threadIdx.x < o) s[threadIdx.x] += s[threadIdx.x + o];
        __syncthreads();
    }
    if (threadIdx.x == 0) bsum[blockIdx.x] = s[0];
}

__global__ __launch_bounds__(512) void k_scan_exc(int* __restrict__ bsum, int nblk)
{
    __shared__ int s[512];
    int t = threadIdx.x;
    s[t] = (t < nblk) ? bsum[t] : 0;
    __syncthreads();
    for (int o = 1; o < 512; o <<= 1) {
        int v = (t >= o) ? s[t - o] : 0;
        __syncthreads();
        s[t] += v;
        __syncthreads();
    }
    if (t < nblk) bsum[t] = (t == 0) ? 0 : s[t - 1];
}

// in-place exclusive scan finalize; writes offs[nb] = total
__global__ __launch_bounds__(256) void k_scan_final(
    int* __restrict__ offs, int nb, const int* __restrict__ bsum)
{
    __shared__ int ts[256];
    int base = blockIdx.x * 2048 + threadIdx.x * 8;
    int loc[8];
    int sum = 0;
#pragma unroll
    for (int u = 0; u < 8; ++u) {
        int v = offs[base + u];
        loc[u] = sum;
        sum += v;
    }
    ts[threadIdx.x] = sum;
    __syncthreads();
    for (int o = 1; o < 256; o <<= 1) {
        int v = (threadIdx.x >= o) ? ts[threadIdx.x - o] : 0;
        __syncthreads();
        ts[threadIdx.x] += v;
        __syncthreads();
    }
    int texc = (threadIdx.x == 0) ? 0 : ts[threadIdx.x - 1];
    int bb = bsum[blockIdx.x];
#pragma unroll
    for (int u = 0; u < 8; ++u) offs[base + u] = bb + texc + loc[u];
    if (blockIdx.x == gridDim.x - 1 && threadIdx.x == 255) offs[nb] = bb + ts[255];
}

// pack: payload (17 bits) | bucket-local (<<17)
template<int NB, int EPT>
__global__ __launch_bounds__(256) void k_sortpass2(
    const int* __restrict__ idx, const int* __restrict__ payload, int shift,
    const int* __restrict__ offsG, uint32_t* __restrict__ pairs)
{
    __shared__ int curs[NB];
    for (int f = threadIdx.x; f < NB; f += 256)
        curs[f] = offsG[f * NBLK + blockIdx.x];
    __syncthreads();
    int lmask = (1 << shift) - 1;
    int base = blockIdx.x * (256 * EPT);
#pragma unroll
    for (int u = 0; u < EPT; ++u) {
        int e = base + u * 256 + threadIdx.x;
        int bk = idx[e];
        int pos = atomicAdd(&curs[bk >> shift], 1);
        pairs[pos] = (uint32_t)payload[e] | ((uint32_t)(bk & lmask) << 17);
    }
}

// ---------------------------------------------------------------------------
// 3) Bin-wise aggregation: in-LDS counting sort, then entry-stream consume
//    with 8 gathers in flight per wave; flush-on-node-change (sorted order),
//    explicit zero rows for gap nodes. Register accumulate, write-once.
// ---------------------------------------------------------------------------
__global__ __launch_bounds__(256) void k_aggcsr(
    const uint32_t* __restrict__ xTb, const int* __restrict__ offsE,
    const uint32_t* __restrict__ pairsE, uint32_t* __restrict__ aggB)
{
    __shared__ uint32_t list[CAP_E];
    __shared__ int offs[65];
    __shared__ int curs[64];
    __shared__ int cnt_s;
    int bin = blockIdx.x;
    if (threadIdx.x == 0) {
        int beg = offsE[bin * NBLK];
        cnt_s = min(offsE[(bin + 1) * NBLK] - beg, CAP_E);
    }
    if (threadIdx.x < 64) curs[threadIdx.x] = 0;
    __syncthreads();
    int beg = offsE[bin * NBLK];
    int cnt = cnt_s;
    for (int i = threadIdx.x; i < cnt; i += 256)
        atomicAdd(&curs[(pairsE[beg + i] >> 17) & 63], 1);
    __syncthreads();
    if (threadIdx.x == 0) {
        int run = 0;
        for (int j = 0; j < 64; ++j) {
            offs[j] = run;
            run += curs[j];
            curs[j] = offs[j];
        }
        offs[64] = run;
    }
    __syncthreads();
    for (int i = threadIdx.x; i < cnt; i += 256) {
        uint32_t u = pairsE[beg + i];
        int p = atomicAdd(&curs[(u >> 17) & 63], 1);
        list[p] = u;
    }
    __syncthreads();

    // entry-stream consume: wave owns nodes [n0,n1), entries [e0,e1)
    int w = threadIdx.x >> 6, lane = threadIdx.x & 63;
    int n0 = w * 16, n1 = n0 + 16;
    int e0 = offs[n0], e1 = offs[n1];
    size_t rowbase = (size_t)(bin * 64) * 64 + lane;
    float sx = 0.f, sy = 0.f;
    int cur = n0;
    for (int e = e0; e < e1; e += 8) {
        int nb = e1 - e;
        uint32_t pr[8], v[8];
#pragma unroll
        for (int j = 0; j < 8; ++j)
            pr[j] = list[e + ((j < nb) ? j : (nb - 1))];
#pragma unroll
        for (int j = 0; j < 8; ++j)
            v[j] = xTb[(size_t)(pr[j] & 0x1FFFF) * 64 + lane];
#pragma unroll
        for (int j = 0; j < 8; ++j) {
            if (j < nb) {
                int d = (pr[j] >> 17) & 63;
                if (d != cur) {
                    aggB[rowbase + (size_t)cur * 64] = pack2(sx, sy);
                    for (int z = cur + 1; z < d; ++z)
                        aggB[rowbase + (size_t)z * 64] = 0u;
                    cur = d;
                    sx = 0.f; sy = 0.f;
                }
                sx += bf_lo(v[j]);
                sy += bf_hi(v[j]);
            }
        }
    }
    aggB[rowbase + (size_t)cur * 64] = pack2(sx, sy);
    for (int z = cur + 1; z < n1; ++z)
        aggB[rowbase + (size_t)z * 64] = 0u;
}

// ---------------------------------------------------------------------------
// 4) MFMA GEMM: h = relu([Wself|Wneigh] @ [x;agg] + bias), bf16 in/out.
//    C/D: col(node)=l&15, row(c)=(l>>4)*4+r  [m89-verified layout]
// ---------------------------------------------------------------------------
__global__ __launch_bounds__(256) void k_gemm(
    const uint32_t* __restrict__ xTb, const uint32_t* __restrict__ aggB,
    const float* __restrict__ Wself, const float* __restrict__ Wneigh,
    const float* __restrict__ bias, uint32_t* __restrict__ hT)
{
    int lane = threadIdx.x & 63;
    int wid = blockIdx.x * 4 + (threadIdx.x >> 6);
    int lr = lane & 15, lq = lane >> 4;

    bf16x8 wf[4][8];
#pragma unroll
    for (int mt = 0; mt < 4; ++mt) {
#pragma unroll
        for (int kt = 0; kt < 8; ++kt) {
            const float* W = (kt < 4) ? Wself : Wneigh;
            const float* p = W + (size_t)(mt * 16 + lr) * 128 + (kt & 3) * 32 + lq * 8;
            bf16x8 v;
#pragma unroll
            for (int j = 0; j < 8; ++j) v[j] = (short)bf16rn(p[j]);
            wf[mt][kt] = v;
        }
    }
    float bv[4][4];
#pragma unroll
    for (int mt = 0; mt < 4; ++mt)
#pragma unroll
        for (int r = 0; r < 4; ++r)
            bv[mt][r] = bias[mt * 16 + lq * 4 + r];

    const int NG = NN / 16;
    int stride = gridDim.x * 4;
    for (int g = wid; g < NG; g += stride) {
        int n = g * 16 + lr;
        const uint32_t* xr = xTb + (size_t)n * 64 + lq * 4;
        const uint32_t* ar = aggB + (size_t)n * 64 + lq * 4;
        bf16x8 bq[8];
#pragma unroll
        for (int kt = 0; kt < 4; ++kt)
            bq[kt] = *reinterpret_cast<const bf16x8*>(xr + kt * 16);
#pragma unroll
        for (int kt = 0; kt < 4; ++kt)
            bq[4 + kt] = *reinterpret_cast<const bf16x8*>(ar + kt * 16);
#pragma unroll
        for (int mt = 0; mt < 4; ++mt) {
            f32x4 acc = {0.f, 0.f, 0.f, 0.f};
#pragma unroll
            for (int kt = 0; kt < 8; ++kt)
                acc = __builtin_amdgcn_mfma_f32_16x16x32_bf16(wf[mt][kt], bq[kt], acc, 0, 0, 0);
            uint32_t u0 = pack2(fmaxf(acc[0] + bv[mt][0], 0.f), fmaxf(acc[1] + bv[mt][1], 0.f));
            uint32_t u1 = pack2(fmaxf(acc[2] + bv[mt][2], 0.f), fmaxf(acc[3] + bv[mt][3], 0.f));
            *reinterpret_cast<uint2*>(hT + (size_t)n * 32 + mt * 8 + lq * 2) = make_uint2(u0, u1);
        }
    }
}

// ---------------------------------------------------------------------------
// 5) Bin-wise unpool: in-LDS counting sort, entry-stream consume with 8
//    gathers in flight, register bit-max (bf16 >= 0), pre-zeroed LDS buf
//    (gap nodes stay zero), transposed coalesced write-once epilogue.
// ---------------------------------------------------------------------------
__global__ __launch_bounds__(256) void k_unpoolcsr(
    const uint16_t* __restrict__ hT16, const int* __restrict__ offsK,
    const uint32_t* __restrict__ pairsK, float* __restrict__ out)
{
    __shared__ uint32_t list[CAP_K];
    __shared__ int offs[129];
    __shared__ int curs[128];
    __shared__ uint16_t buf[128][65];
    __shared__ int cnt_s;
    int bin = blockIdx.x;
    if (threadIdx.x == 0) {
        int beg = offsK[bin * NBLK];
        cnt_s = min(offsK[(bin + 1) * NBLK] - beg, CAP_K);
    }
    if (threadIdx.x < 128) curs[threadIdx.x] = 0;
    for (int f = threadIdx.x; f < 128 * 65; f += 256) ((uint16_t*)buf)[f] = 0;
    __syncthreads();
    int beg = offsK[bin * NBLK];
    int cnt = cnt_s;
    for (int i = threadIdx.x; i < cnt; i += 256)
        atomicAdd(&curs[(pairsK[beg + i] >> 17) & 127], 1);
    __syncthreads();
    if (threadIdx.x == 0) {
        int run = 0;
        for (int j = 0; j < 128; ++j) {
            offs[j] = run;
            run += curs[j];
            curs[j] = offs[j];
        }
        offs[128] = run;
    }
    __syncthreads();
    for (int i = threadIdx.x; i < cnt; i += 256) {
        uint32_t u = pairsK[beg + i];
        int p = atomicAdd(&curs[(u >> 17) & 127], 1);
        list[p] = u;
    }
    __syncthreads();

    int w = threadIdx.x >> 6, lane = threadIdx.x & 63;
    int n0 = w * 32, n1 = n0 + 32;
    int e0 = offs[n0], e1 = offs[n1];
    uint32_t m = 0;
    int cur = n0;
    for (int e = e0; e < e1; e += 8) {
        int nb = e1 - e;
        uint32_t pr[8], v[8];
#pragma unroll
        for (int j = 0; j < 8; ++j)
            pr[j] = list[e + ((j < nb) ? j : (nb - 1))];
#pragma unroll
        for (int j = 0; j < 8; ++j)
            v[j] = hT16[(size_t)(pr[j] & 0x1FFFF) * 64 + lane];
#pragma unroll
        for (int j = 0; j < 8; ++j) {
            if (j < nb) {
                int d = (pr[j] >> 17) & 127;
                if (d != cur) {
                    buf[cur][lane] = (uint16_t)m;
                    cur = d;
                    m = 0;
                }
                m = max(m, v[j]);
            }
        }
    }
    buf[cur][lane] = (uint16_t)m;
    __syncthreads();
    int j0 = bin << 7;
    for (int f = threadIdx.x; f < 64 * 128; f += 256) {
        int c = f >> 7, j = f & 127;
        out[(size_t)c * NF + j0 + j] = __uint_as_float(((uint32_t)buf[j][c]) << 16);
    }
}

// ---------------------------------------------------------------------------
extern "C" void kernel_launch(void* const* d_in, const int* in_sizes, int n_in,
                              void* d_out, int out_size, void* d_ws, size_t ws_size,
                              hipStream_t stream)
{
    const float* a      = (const float*)d_in[0];
    const float* b      = (const float*)d_in[1];
    const float* Wself  = (const float*)d_in[2];
    const float* Wneigh = (const float*)d_in[3];
    const float* bias   = (const float*)d_in[4];
    const int* gather_i = (const int*)d_in[5];
    const int* reduce_i = (const int*)d_in[6];
    const int* up_src   = (const int*)d_in[7];
    const int* up_dst   = (const int*)d_in[8];
    float* out = (float*)d_out;

    // workspace layout (u32 elems); pairsE overlays hT (dead before gemm)
    uint32_t* xTb   = (uint32_t*)d_ws;                   // NN*64
    uint32_t* aggB  = xTb + (size_t)NN * 64;             // NN*64
    uint32_t* hT    = aggB + (size_t)NN * 64;            // NN*32
    uint32_t* pairsK= hT + (size_t)NN * 32;              // KK
    int* offsE      = (int*)(pairsK + KK);               // NB_E*NBLK+1
    int* offsK      = offsE + (size_t)NB_E * NBLK + 1;   // NB_K*NBLK+1
    int* bsum       = offsK + (size_t)NB_K * NBLK + 1;   // 1024
    uint32_t* pairsE= hT;                                // EE (overlay)

    size_t need = ((size_t)NN * 160 + KK +
                   (size_t)NB_E * NBLK + 1 + (size_t)NB_K * NBLK + 1 + 1024) * 4;
    if (ws_size < need) return;  // fail visibly (output stays poisoned)

    // 1) transpose + bf16 pack
    k_transpose<<<NN / 32, 256, 0, stream>>>(a, b, xTb);

    // 2) E-side deterministic bin split (bin = node>>6)
    k_sortpass1<NB_E, EPT_E><<<NBLK, 256, 0, stream>>>(reduce_i, SH_E, offsE);
    k_scan_bsum<<<NB_E * NBLK / 2048, 256, 0, stream>>>(offsE, bsum);
    k_scan_exc<<<1, 512, 0, stream>>>(bsum, NB_E * NBLK / 2048);
    k_scan_final<<<NB_E * NBLK / 2048, 256, 0, stream>>>(offsE, NB_E * NBLK, bsum);
    k_sortpass2<NB_E, EPT_E><<<NBLK, 256, 0, stream>>>(reduce_i, gather_i, SH_E, offsE, pairsE);

    // 3) K-side deterministic bin split (bin = fine>>7)
    k_sortpass1<NB_K, EPT_K><<<NBLK, 256, 0, stream>>>(up_dst, SH_K, offsK);
    k_scan_bsum<<<NB_K * NBLK / 2048, 256, 0, stream>>>(offsK, bsum);
    k_scan_exc<<<1, 512, 0, stream>>>(bsum, NB_K * NBLK / 2048);
    k_scan_final<<<NB_K * NBLK / 2048, 256, 0, stream>>>(offsK, NB_K * NBLK, bsum);
    k_sortpass2<NB_K, EPT_K><<<NBLK, 256, 0, stream>>>(up_dst, up_src, SH_K, offsK, pairsK);

    // 4) bin-wise aggregation (in-LDS CSR, entry-stream register accumulate)
    k_aggcsr<<<NB_E, 256, 0, stream>>>(xTb, offsE, pairsE, aggB);

    // 5) MFMA GEMM + bias + relu -> hT (bf16)
    k_gemm<<<512, 256, 0, stream>>>(xTb, aggB, Wself, Wneigh, bias, hT);

    // 6) bin-wise unpool max (in-LDS CSR, entry-stream register max)
    k_unpoolcsr<<<NB_K, 256, 0, stream>>>((const uint16_t*)hT, offsK, pairsK, out);
}

// Round 8
// 264.256 us; speedup vs baseline: 3.7848x; 1.1180x over previous
//
#include <hip/hip_runtime.h>
#include <stdint.h>

// Problem constants (fixed by the reference)
constexpr int NN = 131072;          // coarse nodes
constexpr int EE = 1048576;         // edges
constexpr int NF = 4 * NN;          // fine nodes = 524288
constexpr int KK = 3 * NF;          // unpool entries = 1572864

constexpr int NBLK = 256;           // blocks per sort side
constexpr int SH_E = 6;             // 64 nodes/bin  -> 2048 bins (E side)
constexpr int SH_K = 7;             // 128 nodes/bin -> 4096 bins (K side)
constexpr int NB_E = NN >> SH_E;    // 2048
constexpr int NB_K = NF >> SH_K;    // 4096
constexpr int EPT_E = EE / NBLK / 256;  // 16 edges/thread
constexpr int EPT_K = KK / NBLK / 256;  // 24 entries/thread
constexpr int CAP_E = 2048;         // >> mean 512 + 10 sigma
constexpr int CAP_K = 1024;         // >> mean 384 + 10 sigma
constexpr int KOFF = NB_E * NBLK;       // K hist offset in combined array
constexpr int NH   = NB_E * NBLK + NB_K * NBLK;  // 1,572,864
constexpr int NSCB = NH / 2048;         // 768 scan blocks

typedef __attribute__((ext_vector_type(8))) short bf16x8;
typedef __attribute__((ext_vector_type(4))) float f32x4;

__device__ inline uint32_t bf16rn(float f) {
    uint32_t u = __float_as_uint(f);
    return (u + 0x7FFFu + ((u >> 16) & 1u)) >> 16;
}
__device__ inline uint32_t pack2(float lo, float hi) {
    return bf16rn(lo) | (bf16rn(hi) << 16);
}
__device__ inline float bf_lo(uint32_t v) { return __uint_as_float(v << 16); }
__device__ inline float bf_hi(uint32_t v) { return __uint_as_float(v & 0xFFFF0000u); }

// ---------------------------------------------------------------------------
// 1) Transpose x = [a;b] (128 x N, f32) -> xTb (N x 128, bf16, node-major)
// ---------------------------------------------------------------------------
__global__ __launch_bounds__(256) void k_transpose(
    const float* __restrict__ a, const float* __restrict__ b,
    uint32_t* __restrict__ xTb)
{
    __shared__ float tile[128][33];
    int i0 = blockIdx.x * 32;
    for (int f = threadIdx.x; f < 128 * 32; f += 256) {
        int c = f >> 5, j = f & 31;
        const float* src = (c < 64) ? a : b;
        tile[c][j] = src[(size_t)(c & 63) * NN + i0 + j];
    }
    __syncthreads();
    for (int f = threadIdx.x; f < 64 * 32; f += 256) {
        int p = f & 63, j = f >> 6;
        xTb[(size_t)(i0 + j) * 64 + p] = pack2(tile[2 * p][j], tile[2 * p + 1][j]);
    }
}

// ---------------------------------------------------------------------------
// 2) Combined deterministic bin split (E side + K side in single dispatches)
// ---------------------------------------------------------------------------
template<int NB, int EPT>
__device__ void pass1_body(const int* __restrict__ idx, int shift,
                           int* __restrict__ histG, int blk, int* hist)
{
    for (int f = threadIdx.x; f < NB; f += 256) hist[f] = 0;
    __syncthreads();
    int base = blk * (256 * EPT);
#pragma unroll
    for (int u = 0; u < EPT; ++u) {
        int b = idx[base + u * 256 + threadIdx.x] >> shift;
        atomicAdd(&hist[b], 1);
    }
    __syncthreads();
    for (int f = threadIdx.x; f < NB; f += 256)
        histG[f * NBLK + blk] = hist[f];
}

__global__ __launch_bounds__(256) void k_pass1(
    const int* __restrict__ reduce_i, const int* __restrict__ up_dst,
    int* __restrict__ histG)
{
    __shared__ int hist[NB_K];   // 16 KB, covers both sides
    if (blockIdx.x < NBLK)
        pass1_body<NB_E, EPT_E>(reduce_i, SH_E, histG, blockIdx.x, hist);
    else
        pass1_body<NB_K, EPT_K>(up_dst, SH_K, histG + KOFF, blockIdx.x - NBLK, hist);
}

// block sums over 2048-chunks of the combined hist array
__global__ __launch_bounds__(256) void k_bsum(
    const int* __restrict__ cnt, int* __restrict__ bsum)
{
    __shared__ int s[256];
    int base = blockIdx.x * 2048;
    int sum = 0;
    for (int j = threadIdx.x; j < 2048; j += 256) sum += cnt[base + j];
    s[threadIdx.x] = sum;
    __syncthreads();
    for (int o = 128; o > 0; o >>= 1) {
        if (threadIdx.x < o) s[threadIdx.x] += s[threadIdx.x + o];
        __syncthreads();
    }
    if (threadIdx.x == 0) bsum[blockIdx.x] = s[0];
}

// fused: block-prefix of bsum (redundant per block) + in-place exclusive scan
__global__ __launch_bounds__(256) void k_final(
    int* __restrict__ offs, const int* __restrict__ bsum)
{
    __shared__ int ts[256];
    // bb = sum of bsum[0..blockIdx.x)
    int partial = 0;
    for (int i = threadIdx.x; i < blockIdx.x; i += 256) partial += bsum[i];
    ts[threadIdx.x] = partial;
    __syncthreads();
    for (int o = 128; o > 0; o >>= 1) {
        if (threadIdx.x < o) ts[threadIdx.x] += ts[threadIdx.x + o];
        __syncthreads();
    }
    int bb = ts[0];
    __syncthreads();

    int base = blockIdx.x * 2048 + threadIdx.x * 8;
    int loc[8];
    int sum = 0;
#pragma unroll
    for (int u = 0; u < 8; ++u) {
        int v = offs[base + u];
        loc[u] = sum;
        sum += v;
    }
    ts[threadIdx.x] = sum;
    __syncthreads();
    for (int o = 1; o < 256; o <<= 1) {
        int v = (threadIdx.x >= o) ? ts[threadIdx.x - o] : 0;
        __syncthreads();
        ts[threadIdx.x] += v;
        __syncthreads();
    }
    int texc = (threadIdx.x == 0) ? 0 : ts[threadIdx.x - 1];
#pragma unroll
    for (int u = 0; u < 8; ++u) offs[base + u] = bb + texc + loc[u];
    if (blockIdx.x == gridDim.x - 1 && threadIdx.x == 255) offs[NH] = bb + ts[255];
}

// pack: payload (17 bits) | bucket-local (<<17)
template<int NB, int EPT>
__device__ void pass2_body(const int* __restrict__ idx,
                           const int* __restrict__ payload, int shift,
                           const int* __restrict__ offsG, int sub,
                           uint32_t* __restrict__ pairs, int blk, int* curs)
{
    for (int f = threadIdx.x; f < NB; f += 256)
        curs[f] = offsG[f * NBLK + blk] - sub;
    __syncthreads();
    int lmask = (1 << shift) - 1;
    int base = blk * (256 * EPT);
#pragma unroll
    for (int u = 0; u < EPT; ++u) {
        int e = base + u * 256 + threadIdx.x;
        int bk = idx[e];
        int pos = atomicAdd(&curs[bk >> shift], 1);
        pairs[pos] = (uint32_t)payload[e] | ((uint32_t)(bk & lmask) << 17);
    }
}

__global__ __launch_bounds__(256) void k_pass2(
    const int* __restrict__ reduce_i, const int* __restrict__ gather_i,
    const int* __restrict__ up_dst, const int* __restrict__ up_src,
    const int* __restrict__ offs,
    uint32_t* __restrict__ pairsE, uint32_t* __restrict__ pairsK)
{
    __shared__ int curs[NB_K];   // 16 KB
    if (blockIdx.x < NBLK)
        pass2_body<NB_E, EPT_E>(reduce_i, gather_i, SH_E, offs, 0,
                                pairsE, blockIdx.x, curs);
    else
        pass2_body<NB_K, EPT_K>(up_dst, up_src, SH_K, offs + KOFF, EE,
                                pairsK, blockIdx.x - NBLK, curs);
}

// ---------------------------------------------------------------------------
// 3) Bin-wise aggregation: in-LDS counting sort, 16-deep entry-stream MLP,
//    flush-on-node-change, register accumulate, write-once.
// ---------------------------------------------------------------------------
__global__ __launch_bounds__(256) void k_aggcsr(
    const uint32_t* __restrict__ xTb, const int* __restrict__ offsE,
    const uint32_t* __restrict__ pairsE, uint32_t* __restrict__ aggB)
{
    __shared__ uint32_t list[CAP_E];
    __shared__ int offs[65];
    __shared__ int curs[64];
    __shared__ int cnt_s;
    int bin = blockIdx.x;
    if (threadIdx.x == 0) {
        int beg = offsE[bin * NBLK];
        cnt_s = min(offsE[(bin + 1) * NBLK] - beg, CAP_E);
    }
    if (threadIdx.x < 64) curs[threadIdx.x] = 0;
    __syncthreads();
    int beg = offsE[bin * NBLK];
    int cnt = cnt_s;
    for (int i = threadIdx.x; i < cnt; i += 256)
        atomicAdd(&curs[(pairsE[beg + i] >> 17) & 63], 1);
    __syncthreads();
    if (threadIdx.x == 0) {
        int run = 0;
        for (int j = 0; j < 64; ++j) {
            offs[j] = run;
            run += curs[j];
            curs[j] = offs[j];
        }
        offs[64] = run;
    }
    __syncthreads();
    for (int i = threadIdx.x; i < cnt; i += 256) {
        uint32_t u = pairsE[beg + i];
        int p = atomicAdd(&curs[(u >> 17) & 63], 1);
        list[p] = u;
    }
    __syncthreads();

    // entry-stream consume, 16 gathers in flight
    int w = threadIdx.x >> 6, lane = threadIdx.x & 63;
    int n0 = w * 16, n1 = n0 + 16;
    int e0 = offs[n0], e1 = offs[n1];
    size_t rowbase = (size_t)(bin * 64) * 64 + lane;
    float sx = 0.f, sy = 0.f;
    int cur = n0;
    for (int e = e0; e < e1; e += 16) {
        int nb = e1 - e;
        uint32_t pr[16], v[16];
#pragma unroll
        for (int j = 0; j < 16; ++j)
            pr[j] = list[e + ((j < nb) ? j : (nb - 1))];
#pragma unroll
        for (int j = 0; j < 16; ++j)
            v[j] = xTb[(size_t)(pr[j] & 0x1FFFF) * 64 + lane];
#pragma unroll
        for (int j = 0; j < 16; ++j) {
            if (j < nb) {
                int d = (pr[j] >> 17) & 63;
                if (d != cur) {
                    aggB[rowbase + (size_t)cur * 64] = pack2(sx, sy);
                    for (int z = cur + 1; z < d; ++z)
                        aggB[rowbase + (size_t)z * 64] = 0u;
                    cur = d;
                    sx = 0.f; sy = 0.f;
                }
                sx += bf_lo(v[j]);
                sy += bf_hi(v[j]);
            }
        }
    }
    aggB[rowbase + (size_t)cur * 64] = pack2(sx, sy);
    for (int z = cur + 1; z < n1; ++z)
        aggB[rowbase + (size_t)z * 64] = 0u;
}

// ---------------------------------------------------------------------------
// 4) MFMA GEMM: h = relu([Wself|Wneigh] @ [x;agg] + bias), bf16 in/out.
//    C/D: col(node)=l&15, row(c)=(l>>4)*4+r  [m89-verified layout]
// ---------------------------------------------------------------------------
__global__ __launch_bounds__(256) void k_gemm(
    const uint32_t* __restrict__ xTb, const uint32_t* __restrict__ aggB,
    const float* __restrict__ Wself, const float* __restrict__ Wneigh,
    const float* __restrict__ bias, uint32_t* __restrict__ hT)
{
    int lane = threadIdx.x & 63;
    int wid = blockIdx.x * 4 + (threadIdx.x >> 6);
    int lr = lane & 15, lq = lane >> 4;

    bf16x8 wf[4][8];
#pragma unroll
    for (int mt = 0; mt < 4; ++mt) {
#pragma unroll
        for (int kt = 0; kt < 8; ++kt) {
            const float* W = (kt < 4) ? Wself : Wneigh;
            const float* p = W + (size_t)(mt * 16 + lr) * 128 + (kt & 3) * 32 + lq * 8;
            bf16x8 v;
#pragma unroll
            for (int j = 0; j < 8; ++j) v[j] = (short)bf16rn(p[j]);
            wf[mt][kt] = v;
        }
    }
    float bv[4][4];
#pragma unroll
    for (int mt = 0; mt < 4; ++mt)
#pragma unroll
        for (int r = 0; r < 4; ++r)
            bv[mt][r] = bias[mt * 16 + lq * 4 + r];

    const int NG = NN / 16;
    int stride = gridDim.x * 4;
    for (int g = wid; g < NG; g += stride) {
        int n = g * 16 + lr;
        const uint32_t* xr = xTb + (size_t)n * 64 + lq * 4;
        const uint32_t* ar = aggB + (size_t)n * 64 + lq * 4;
        bf16x8 bq[8];
#pragma unroll
        for (int kt = 0; kt < 4; ++kt)
            bq[kt] = *reinterpret_cast<const bf16x8*>(xr + kt * 16);
#pragma unroll
        for (int kt = 0; kt < 4; ++kt)
            bq[4 + kt] = *reinterpret_cast<const bf16x8*>(ar + kt * 16);
#pragma unroll
        for (int mt = 0; mt < 4; ++mt) {
            f32x4 acc = {0.f, 0.f, 0.f, 0.f};
#pragma unroll
            for (int kt = 0; kt < 8; ++kt)
                acc = __builtin_amdgcn_mfma_f32_16x16x32_bf16(wf[mt][kt], bq[kt], acc, 0, 0, 0);
            uint32_t u0 = pack2(fmaxf(acc[0] + bv[mt][0], 0.f), fmaxf(acc[1] + bv[mt][1], 0.f));
            uint32_t u1 = pack2(fmaxf(acc[2] + bv[mt][2], 0.f), fmaxf(acc[3] + bv[mt][3], 0.f));
            *reinterpret_cast<uint2*>(hT + (size_t)n * 32 + mt * 8 + lq * 2) = make_uint2(u0, u1);
        }
    }
}

// ---------------------------------------------------------------------------
// 5) Bin-wise unpool: in-LDS counting sort, 16-deep entry-stream MLP,
//    register bit-max (bf16 >= 0), pre-zeroed LDS buf, coalesced epilogue.
// ---------------------------------------------------------------------------
__global__ __launch_bounds__(256) void k_unpoolcsr(
    const uint16_t* __restrict__ hT16, const int* __restrict__ offsK,
    const uint32_t* __restrict__ pairsK, float* __restrict__ out)
{
    __shared__ uint32_t list[CAP_K];
    __shared__ int offs[129];
    __shared__ int curs[128];
    __shared__ uint16_t buf[128][65];
    __shared__ int cnt_s;
    int bin = blockIdx.x;
    if (threadIdx.x == 0) {
        int beg = offsK[bin * NBLK] - EE;
        cnt_s = min(offsK[(bin + 1) * NBLK] - EE - beg, CAP_K);
    }
    if (threadIdx.x < 128) curs[threadIdx.x] = 0;
    for (int f = threadIdx.x; f < 128 * 65; f += 256) ((uint16_t*)buf)[f] = 0;
    __syncthreads();
    int beg = offsK[bin * NBLK] - EE;
    int cnt = cnt_s;
    for (int i = threadIdx.x; i < cnt; i += 256)
        atomicAdd(&curs[(pairsK[beg + i] >> 17) & 127], 1);
    __syncthreads();
    if (threadIdx.x == 0) {
        int run = 0;
        for (int j = 0; j < 128; ++j) {
            offs[j] = run;
            run += curs[j];
            curs[j] = offs[j];
        }
        offs[128] = run;
    }
    __syncthreads();
    for (int i = threadIdx.x; i < cnt; i += 256) {
        uint32_t u = pairsK[beg + i];
        int p = atomicAdd(&curs[(u >> 17) & 127], 1);
        list[p] = u;
    }
    __syncthreads();

    int w = threadIdx.x >> 6, lane = threadIdx.x & 63;
    int n0 = w * 32, n1 = n0 + 32;
    int e0 = offs[n0], e1 = offs[n1];
    uint32_t m = 0;
    int cur = n0;
    for (int e = e0; e < e1; e += 16) {
        int nb = e1 - e;
        uint32_t pr[16], v[16];
#pragma unroll
        for (int j = 0; j < 16; ++j)
            pr[j] = list[e + ((j < nb) ? j : (nb - 1))];
#pragma unroll
        for (int j = 0; j < 16; ++j)
            v[j] = hT16[(size_t)(pr[j] & 0x1FFFF) * 64 + lane];
#pragma unroll
        for (int j = 0; j < 16; ++j) {
            if (j < nb) {
                int d = (pr[j] >> 17) & 127;
                if (d != cur) {
                    buf[cur][lane] = (uint16_t)m;
                    cur = d;
                    m = 0;
                }
                m = max(m, v[j]);
            }
        }
    }
    buf[cur][lane] = (uint16_t)m;
    __syncthreads();
    int j0 = bin << 7;
    for (int f = threadIdx.x; f < 64 * 128; f += 256) {
        int c = f >> 7, j = f & 127;
        out[(size_t)c * NF + j0 + j] = __uint_as_float(((uint32_t)buf[j][c]) << 16);
    }
}

// ---------------------------------------------------------------------------
extern "C" void kernel_launch(void* const* d_in, const int* in_sizes, int n_in,
                              void* d_out, int out_size, void* d_ws, size_t ws_size,
                              hipStream_t stream)
{
    const float* a      = (const float*)d_in[0];
    const float* b      = (const float*)d_in[1];
    const float* Wself  = (const float*)d_in[2];
    const float* Wneigh = (const float*)d_in[3];
    const float* bias   = (const float*)d_in[4];
    const int* gather_i = (const int*)d_in[5];
    const int* reduce_i = (const int*)d_in[6];
    const int* up_src   = (const int*)d_in[7];
    const int* up_dst   = (const int*)d_in[8];
    float* out = (float*)d_out;

    // workspace layout (u32 elems); pairsE overlays hT (dead before gemm)
    uint32_t* xTb   = (uint32_t*)d_ws;                   // NN*64
    uint32_t* aggB  = xTb + (size_t)NN * 64;             // NN*64
    uint32_t* hT    = aggB + (size_t)NN * 64;            // NN*32
    uint32_t* pairsK= hT + (size_t)NN * 32;              // KK
    int* offs       = (int*)(pairsK + KK);               // NH+1 (combined E|K)
    int* bsum       = offs + (size_t)NH + 1;             // NSCB
    uint32_t* pairsE= hT;                                // EE (overlay)

    size_t need = ((size_t)NN * 160 + KK + (size_t)NH + 1 + NSCB) * 4;
    if (ws_size < need) return;  // fail visibly (output stays poisoned)

    // 1) transpose + bf16 pack
    k_transpose<<<NN / 32, 256, 0, stream>>>(a, b, xTb);

    // 2) combined bin split: hist -> scan -> scatter (5 dispatches total)
    k_pass1<<<2 * NBLK, 256, 0, stream>>>(reduce_i, up_dst, offs);
    k_bsum<<<NSCB, 256, 0, stream>>>(offs, bsum);
    k_final<<<NSCB, 256, 0, stream>>>(offs, bsum);
    k_pass2<<<2 * NBLK, 256, 0, stream>>>(reduce_i, gather_i, up_dst, up_src,
                                          offs, pairsE, pairsK);

    // 3) bin-wise aggregation (in-LDS CSR, 16-deep register accumulate)
    k_aggcsr<<<NB_E, 256, 0, stream>>>(xTb, offs, pairsE, aggB);

    // 4) MFMA GEMM + bias + relu -> hT (bf16)
    k_gemm<<<512, 256, 0, stream>>>(xTb, aggB, Wself, Wneigh, bias, hT);

    // 5) bin-wise unpool max (in-LDS CSR, 16-deep register max)
    k_unpoolcsr<<<NB_K, 256, 0, stream>>>((const uint16_t*)hT, offs + KOFF,
                                          pairsK, out);
}